// Round 19
// baseline (793.838 us; speedup 1.0000x reference)
//
#include <hip/hip_runtime.h>
#include <cstdint>

#define NLAYER 4
#define DMODEL 1024
#define NHEAD 16
#define DHEAD 64
#define DINNER 4096
#define QLEN 512
#define MLEN 512
#define KLEN (QLEN + MLEN)
#define BATCH 4
#define ND (NHEAD * DHEAD)

typedef unsigned short u16;
typedef __attribute__((ext_vector_type(8))) short short8;
typedef __attribute__((ext_vector_type(4))) float f32x4;
typedef __attribute__((address_space(1))) const unsigned int guint;
typedef __attribute__((address_space(3))) unsigned int luint;

__device__ __forceinline__ u16 f2b(float x) {
  unsigned u = __builtin_bit_cast(unsigned, x);
  return (u16)((u + 0x7fffu + ((u >> 16) & 1u)) >> 16);
}
__device__ __forceinline__ float b2f(u16 h) {
  return __builtin_bit_cast(float, (unsigned)h << 16);
}

// ======== init_all: conversions + embedding + pos-emb, ONE dispatch ========
// conv blocks [0,30720); [30720,32768): embed; [32768,33792): posemb
__global__ __launch_bounds__(256) void init_all(
    const float* __restrict__ s0, const float* __restrict__ s1,
    const float* __restrict__ s2, const float* __restrict__ s3,
    const float* __restrict__ s4, const float* __restrict__ s5,
    u16* __restrict__ d0, u16* __restrict__ d1, u16* __restrict__ d2,
    u16* __restrict__ d3, u16* __restrict__ d4, u16* __restrict__ d5,
    const int* __restrict__ tok, const float* __restrict__ emb,
    float* __restrict__ h, u16* __restrict__ hb, u16* __restrict__ pe)
{
  const int blk = blockIdx.x;
  const int t = threadIdx.x;
  if (blk < 30720) {
    int i = blk * 256 + t;
    const float* s; u16* d;
    if      (i < 1048576) { s = s0; d = d0; }
    else if (i < 2621440) { s = s1; d = d1; i -= 1048576; }
    else if (i < 3145728) { s = s2; d = d2; i -= 2621440; }
    else if (i < 3670016) { s = s3; d = d3; i -= 3145728; }
    else if (i < 5767168) { s = s4; d = d4; i -= 3670016; }
    else                  { s = s5; d = d5; i -= 5767168; }
    const float4 a = ((const float4*)s)[2 * i], b = ((const float4*)s)[2 * i + 1];
    union { u16 u[8]; float4 v; } p;
    p.u[0] = f2b(a.x); p.u[1] = f2b(a.y); p.u[2] = f2b(a.z); p.u[3] = f2b(a.w);
    p.u[4] = f2b(b.x); p.u[5] = f2b(b.y); p.u[6] = f2b(b.z); p.u[7] = f2b(b.w);
    ((float4*)d)[i] = p.v;
  } else if (blk < 32768) {
    const int e = blk - 30720;
    const int q = e >> 2, b = e & 3;
    const int id = tok[b * QLEN + q];
    const float4 v = ((const float4*)(emb + (size_t)id * DMODEL))[t];
    const size_t row = (size_t)q * BATCH + b;
    ((float4*)(h + row * DMODEL))[t] = v;
    union { u16 u[4]; float2 f; } p;
    p.u[0] = f2b(v.x); p.u[1] = f2b(v.y); p.u[2] = f2b(v.z); p.u[3] = f2b(v.w);
    *(float2*)(hb + row * DMODEL + t * 4) = p.f;
  } else {
    const int k = blk - 32768;
    const float pos = (float)(KLEN - 1 - k);
    for (int i = t; i < DMODEL / 2; i += 256) {
      const float inv_freq = powf(10000.0f, -(float)(2 * i) / (float)DMODEL);
      const float a = pos * inv_freq;
      pe[(size_t)k * DMODEL + i] = f2b(sinf(a));
      pe[(size_t)k * DMODEL + DMODEL / 2 + i] = f2b(cosf(a));
    }
  }
}

// ======== mgemm4: counted vmcnt(8) + raw double barrier + setprio (MF=4) ========
template<int OUTBF, int RELU, int BIAS>
__global__ __launch_bounds__(256) void mgemm4(
    const u16* __restrict__ A0, const u16* __restrict__ A1, int splitRow,
    const u16* __restrict__ B, void* __restrict__ Cp,
    const float* __restrict__ bias, int Kd, long sa, long sb, long sc)
{
  constexpr int MF = 4;
  constexpr int BM = 128;
  constexpr int NGA = 16;
  constexpr int GPW = 8;
  __shared__ u16 As[2][BM][64];
  __shared__ u16 Bs[2][128][64];
  const int nwg = gridDim.x * gridDim.y;
  int wg = blockIdx.y * gridDim.x + blockIdx.x;
  wg = (wg & 7) * (nwg >> 3) + (wg >> 3);
  const int bm = (wg % gridDim.x) * BM;
  const int bn = (wg / gridDim.x) * 128;
  const int t = threadIdx.x, wave = t >> 6, lane = t & 63;
  const int wm = (wave >> 1) * (MF * 16), wn = (wave & 1) * 64;
  const int lrow = lane & 15, lk = lane >> 4;
  const int gsw = ((lane & 7) ^ (lane >> 3)) * 8;
  const u16* gptr[GPW];
  int row8[GPW];
  bool isA[GPW];
#pragma unroll
  for (int c = 0; c < GPW; ++c) {
    const int g = wave * GPW + c;
    isA[c] = g < NGA;
    row8[c] = (isA[c] ? g : g - NGA) * 8;
    const int row = row8[c] + (lane >> 3);
    if (isA[c]) {
      const int ga = bm + row;
      gptr[c] = ((A1 != nullptr && ga >= splitRow)
                     ? A1 + (size_t)(ga - splitRow) * sa
                     : A0 + (size_t)ga * sa) + gsw;
    } else {
      gptr[c] = B + (size_t)(bn + row) * sb + gsw;
    }
  }
  auto STAGE = [&](int buf, int k0) {
#pragma unroll
    for (int c = 0; c < GPW; ++c) {
      luint* dst = isA[c] ? (luint*)&As[buf][row8[c]][0] : (luint*)&Bs[buf][row8[c]][0];
      __builtin_amdgcn_global_load_lds((guint*)(gptr[c] + k0), dst, 16, 0, 0);
    }
  };
  f32x4 acc[MF][4] = {};
  const int nt = Kd >> 6;
  STAGE(0, 0);
  for (int ti = 0; ti < nt; ++ti) {
    const int cur = ti & 1;
    if (ti + 1 < nt) {
      STAGE(cur ^ 1, (ti + 1) << 6);
      asm volatile("s_waitcnt vmcnt(8)" ::: "memory");
    } else {
      asm volatile("s_waitcnt vmcnt(0)" ::: "memory");
    }
    __builtin_amdgcn_s_barrier();
    __builtin_amdgcn_sched_barrier(0);
    __builtin_amdgcn_s_setprio(1);
#pragma unroll
    for (int ks = 0; ks < 2; ++ks) {
      short8 af[MF], bf[4];
#pragma unroll
      for (int x = 0; x < MF; ++x) {
        const int ra = wm + x * 16 + lrow;
        af[x] = *(const short8*)((const u16*)&As[cur][0][0] + ra * 64 + (((ks * 4 + lk) ^ (ra & 7)) * 8));
      }
#pragma unroll
      for (int x = 0; x < 4; ++x) {
        const int rb = wn + x * 16 + lrow;
        bf[x] = *(const short8*)((const u16*)&Bs[cur][0][0] + rb * 64 + (((ks * 4 + lk) ^ (rb & 7)) * 8));
      }
#pragma unroll
      for (int mi = 0; mi < MF; ++mi)
#pragma unroll
        for (int ni = 0; ni < 4; ++ni)
          acc[mi][ni] = __builtin_amdgcn_mfma_f32_16x16x32_bf16(af[mi], bf[ni], acc[mi][ni], 0, 0, 0);
    }
    __builtin_amdgcn_s_setprio(0);
    asm volatile("s_waitcnt lgkmcnt(0)" ::: "memory");
    __builtin_amdgcn_s_barrier();
    __builtin_amdgcn_sched_barrier(0);
  }
  const size_t row0 = bm + wm + lk * 4;
  const size_t col0 = bn + wn + lrow;
#pragma unroll
  for (int mi = 0; mi < MF; ++mi)
#pragma unroll
    for (int r = 0; r < 4; ++r) {
      const size_t row = row0 + mi * 16 + r;
#pragma unroll
      for (int ni = 0; ni < 4; ++ni) {
        float v = acc[mi][ni][r];
        if (BIAS) v += bias[col0 + ni * 16];
        if (RELU) v = fmaxf(v, 0.0f);
        if (OUTBF) ((u16*)Cp)[row * sc + col0 + ni * 16] = f2b(v);
        else       ((float*)Cp)[row * sc + col0 + ni * 16] = v;
      }
    }
}

// ======== mgemm4k: split-K=2, MF=2, counted vmcnt(6) + setprio, bf16 partials ========
template<int BIAS>
__global__ __launch_bounds__(256) void mgemm4k(
    const u16* __restrict__ A, const u16* __restrict__ B,
    u16* __restrict__ C0, u16* __restrict__ C1,
    const float* __restrict__ bias, int KdH, long sa, long sb, long sc)
{
  constexpr int MF = 2;
  constexpr int BM = 64;
  constexpr int NGA = 8;
  constexpr int GPW = 6;
  __shared__ u16 As[2][BM][64];
  __shared__ u16 Bs[2][128][64];
  const int z = blockIdx.z;
  A += (size_t)z * KdH;
  B += (size_t)z * KdH;
  u16* C = z ? C1 : C0;
  const int nwg = gridDim.x * gridDim.y;
  int wg = blockIdx.y * gridDim.x + blockIdx.x;
  wg = (wg & 7) * (nwg >> 3) + (wg >> 3);
  const int bm = (wg % gridDim.x) * BM;
  const int bn = (wg / gridDim.x) * 128;
  const int t = threadIdx.x, wave = t >> 6, lane = t & 63;
  const int wm = (wave >> 1) * (MF * 16), wn = (wave & 1) * 64;
  const int lrow = lane & 15, lk = lane >> 4;
  const int gsw = ((lane & 7) ^ (lane >> 3)) * 8;
  const u16* gptr[GPW];
  int row8[GPW];
  bool isA[GPW];
#pragma unroll
  for (int c = 0; c < GPW; ++c) {
    const int g = wave * GPW + c;
    isA[c] = g < NGA;
    row8[c] = (isA[c] ? g : g - NGA) * 8;
    const int row = row8[c] + (lane >> 3);
    gptr[c] = isA[c] ? A + (size_t)(bm + row) * sa + gsw
                     : B + (size_t)(bn + row) * sb + gsw;
  }
  auto STAGE = [&](int buf, int k0) {
#pragma unroll
    for (int c = 0; c < GPW; ++c) {
      luint* dst = isA[c] ? (luint*)&As[buf][row8[c]][0] : (luint*)&Bs[buf][row8[c]][0];
      __builtin_amdgcn_global_load_lds((guint*)(gptr[c] + k0), dst, 16, 0, 0);
    }
  };
  f32x4 acc[MF][4] = {};
  const int nt = KdH >> 6;
  STAGE(0, 0);
  for (int ti = 0; ti < nt; ++ti) {
    const int cur = ti & 1;
    if (ti + 1 < nt) {
      STAGE(cur ^ 1, (ti + 1) << 6);
      asm volatile("s_waitcnt vmcnt(6)" ::: "memory");
    } else {
      asm volatile("s_waitcnt vmcnt(0)" ::: "memory");
    }
    __builtin_amdgcn_s_barrier();
    __builtin_amdgcn_sched_barrier(0);
    __builtin_amdgcn_s_setprio(1);
#pragma unroll
    for (int ks = 0; ks < 2; ++ks) {
      short8 af[MF], bf[4];
#pragma unroll
      for (int x = 0; x < MF; ++x) {
        const int ra = wm + x * 16 + lrow;
        af[x] = *(const short8*)((const u16*)&As[cur][0][0] + ra * 64 + (((ks * 4 + lk) ^ (ra & 7)) * 8));
      }
#pragma unroll
      for (int x = 0; x < 4; ++x) {
        const int rb = wn + x * 16 + lrow;
        bf[x] = *(const short8*)((const u16*)&Bs[cur][0][0] + rb * 64 + (((ks * 4 + lk) ^ (rb & 7)) * 8));
      }
#pragma unroll
      for (int mi = 0; mi < MF; ++mi)
#pragma unroll
        for (int ni = 0; ni < 4; ++ni)
          acc[mi][ni] = __builtin_amdgcn_mfma_f32_16x16x32_bf16(af[mi], bf[ni], acc[mi][ni], 0, 0, 0);
    }
    __builtin_amdgcn_s_setprio(0);
    asm volatile("s_waitcnt lgkmcnt(0)" ::: "memory");
    __builtin_amdgcn_s_barrier();
    __builtin_amdgcn_sched_barrier(0);
  }
  const size_t row0 = bm + wm + lk * 4;
  const size_t col0 = bn + wn + lrow;
#pragma unroll
  for (int mi = 0; mi < MF; ++mi)
#pragma unroll
    for (int r = 0; r < 4; ++r) {
      const size_t row = row0 + mi * 16 + r;
#pragma unroll
      for (int ni = 0; ni < 4; ++ni) {
        float v = acc[mi][ni][r];
        if (BIAS && z == 0) v += bias[col0 + ni * 16];
        C[row * sc + col0 + ni * 16] = f2b(v);
      }
    }
}

// ======== mgemm3: 2-phase double-buffered NT GEMM (validated; r GEMM) ========
template<int MF, int OUTBF, int RELU, int BIAS>
__global__ __launch_bounds__(256) void mgemm3(
    const u16* __restrict__ A0, const u16* __restrict__ A1, int splitRow,
    const u16* __restrict__ B, void* __restrict__ Cp,
    const float* __restrict__ bias, int Kd, long sa, long sb, long sc,
    long bzs, long czs)
{
  constexpr int BM = MF * 32;
  constexpr int NGA = BM / 8;
  constexpr int GPW = (NGA + 16) / 4;
  __shared__ u16 As[2][BM][64];
  __shared__ u16 Bs[2][128][64];
  const int zz = blockIdx.z;
  B += (size_t)zz * bzs;
  const int nwg = gridDim.x * gridDim.y;
  int wg = blockIdx.y * gridDim.x + blockIdx.x;
  wg = (wg & 7) * (nwg >> 3) + (wg >> 3);
  const int bm = (wg % gridDim.x) * BM;
  const int bn = (wg / gridDim.x) * 128;
  const int t = threadIdx.x, wave = t >> 6, lane = t & 63;
  const int wm = (wave >> 1) * (MF * 16), wn = (wave & 1) * 64;
  const int lrow = lane & 15, lk = lane >> 4;
  const int gsw = ((lane & 7) ^ (lane >> 3)) * 8;
  const u16* gptr[GPW];
  int row8[GPW];
  bool isA[GPW];
#pragma unroll
  for (int c = 0; c < GPW; ++c) {
    const int g = wave * GPW + c;
    isA[c] = g < NGA;
    row8[c] = (isA[c] ? g : g - NGA) * 8;
    const int row = row8[c] + (lane >> 3);
    if (isA[c]) {
      const int ga = bm + row;
      gptr[c] = ((A1 != nullptr && ga >= splitRow)
                     ? A1 + (size_t)(ga - splitRow) * sa
                     : A0 + (size_t)ga * sa) + gsw;
    } else {
      gptr[c] = B + (size_t)(bn + row) * sb + gsw;
    }
  }
  auto STAGE = [&](int buf, int k0) {
#pragma unroll
    for (int c = 0; c < GPW; ++c) {
      luint* dst = isA[c] ? (luint*)&As[buf][row8[c]][0] : (luint*)&Bs[buf][row8[c]][0];
      __builtin_amdgcn_global_load_lds((guint*)(gptr[c] + k0), dst, 16, 0, 0);
    }
  };
  f32x4 acc[MF][4] = {};
  const int nt = Kd >> 6;
  STAGE(0, 0);
  __syncthreads();
  for (int ti = 0; ti < nt; ++ti) {
    const int cur = ti & 1;
    if (ti + 1 < nt) STAGE(cur ^ 1, (ti + 1) << 6);
#pragma unroll
    for (int ks = 0; ks < 2; ++ks) {
      short8 af[MF], bf[4];
#pragma unroll
      for (int x = 0; x < MF; ++x) {
        const int ra = wm + x * 16 + lrow;
        af[x] = *(const short8*)((const u16*)&As[cur][0][0] + ra * 64 + (((ks * 4 + lk) ^ (ra & 7)) * 8));
      }
#pragma unroll
      for (int x = 0; x < 4; ++x) {
        const int rb = wn + x * 16 + lrow;
        bf[x] = *(const short8*)((const u16*)&Bs[cur][0][0] + rb * 64 + (((ks * 4 + lk) ^ (rb & 7)) * 8));
      }
#pragma unroll
      for (int mi = 0; mi < MF; ++mi)
#pragma unroll
        for (int ni = 0; ni < 4; ++ni)
          acc[mi][ni] = __builtin_amdgcn_mfma_f32_16x16x32_bf16(af[mi], bf[ni], acc[mi][ni], 0, 0, 0);
    }
    __syncthreads();
  }
  const size_t row0 = bm + wm + lk * 4;
  const size_t col0 = bn + wn + lrow;
#pragma unroll
  for (int mi = 0; mi < MF; ++mi)
#pragma unroll
    for (int r = 0; r < 4; ++r) {
      const size_t row = row0 + mi * 16 + r;
#pragma unroll
      for (int ni = 0; ni < 4; ++ni) {
        float v = acc[mi][ni][r];
        if (BIAS) v += bias[col0 + ni * 16];
        if (RELU) v = fmaxf(v, 0.0f);
        if (OUTBF) ((u16*)Cp + (size_t)zz * czs)[row * sc + col0 + ni * 16] = f2b(v);
        else       ((float*)Cp + (size_t)zz * czs)[row * sc + col0 + ni * 16] = v;
      }
    }
}

// ======== attn_prep: vtrans + bd_gemm in ONE dispatch (block ranges) ========
__global__ __launch_bounds__(256) void attn_prep(
    const u16* __restrict__ qkvb, const u16* __restrict__ rb,
    const float* __restrict__ rrb, u16* __restrict__ S, u16* __restrict__ Vt)
{
  __shared__ u16 sh[2 * 128 * 72];
  const int idx = blockIdx.x;
  const int t = threadIdx.x;
  if (idx < 1024) {
    u16 (*T)[72] = (u16(*)[72])sh;
    const int j0 = (idx & 15) * 64;
    const int bn = idx >> 4, b = bn >> 4, n = bn & 15;
    const int jl = t >> 3, ch = t & 7;
#pragma unroll
    for (int p = 0; p < 2; ++p) {
      const int jj = p * 32 + jl;
      const float4 v = *(const float4*)(qkvb + ((size_t)(j0 + jj) * BATCH + b) * (3 * ND)
                                        + 2 * ND + n * 64 + ch * 8);
      *(float4*)&T[jj][ch * 8] = v;
    }
    __syncthreads();
#pragma unroll
    for (int p = 0; p < 2; ++p) {
      const int dd = p * 32 + jl;
      union { u16 u[8]; float4 v; } o;
#pragma unroll
      for (int e = 0; e < 8; ++e) o.u[e] = T[ch * 8 + e][dd];
      *(float4*)(Vt + ((size_t)(b * 16 + n) * 64 + dd) * 1024 + j0 + ch * 8) = o.v;
    }
    return;
  }
  const int i2 = idx - 1024;
  const int bm = (i2 & 3) * 128, bn = ((i2 >> 2) & 7) * 128;
  if (bm + bn < 257) return;
  const int z = i2 >> 5, zb = z & 3, zn = z >> 2;
  u16 (*As)[72] = (u16(*)[72])sh;
  u16 (*Bs)[72] = (u16(*)[72])(sh + 128 * 72);
  const u16* Ab = qkvb + ((size_t)(QLEN * BATCH) + zb) * (3 * ND) + zn * 64;
  const u16* Bb = rb + zn * 64;
  u16* Sb = S + (size_t)(zn * 4 + zb) * 524288;
  const int wave = t >> 6, lane = t & 63;
  const int wm = (wave >> 1) * 64, wn = (wave & 1) * 64;
  const int lrow = lane & 15, lk = lane >> 4;
  const int sr = t >> 2, sc = (t & 3) * 16;
#pragma unroll
  for (int p = 0; p < 2; ++p) {
    const int row = sr + p * 64;
    union { u16 u[16]; float4 v[2]; } av;
    av.v[0] = *(const float4*)(Ab + (size_t)(bm + row) * (BATCH * 3 * ND) + sc);
    av.v[1] = *(const float4*)(Ab + (size_t)(bm + row) * (BATCH * 3 * ND) + sc + 8);
#pragma unroll
    for (int e = 0; e < 16; ++e) av.u[e] = f2b(b2f(av.u[e]) + rrb[zn * 64 + sc + e]);
    *(float4*)&As[row][sc] = av.v[0];
    *(float4*)&As[row][sc + 8] = av.v[1];
    const float4 b0 = *(const float4*)(Bb + (size_t)(bn + row) * 1024 + sc);
    const float4 b1 = *(const float4*)(Bb + (size_t)(bn + row) * 1024 + sc + 8);
    *(float4*)&Bs[row][sc] = b0;
    *(float4*)&Bs[row][sc + 8] = b1;
  }
  __syncthreads();
  f32x4 acc[4][4] = {};
#pragma unroll
  for (int ks = 0; ks < 2; ++ks) {
    short8 af[4], bf[4];
#pragma unroll
    for (int x = 0; x < 4; ++x) af[x] = *(const short8*)&As[wm + x * 16 + lrow][ks * 32 + lk * 8];
#pragma unroll
    for (int x = 0; x < 4; ++x) bf[x] = *(const short8*)&Bs[wn + x * 16 + lrow][ks * 32 + lk * 8];
#pragma unroll
    for (int mi = 0; mi < 4; ++mi)
#pragma unroll
      for (int ni = 0; ni < 4; ++ni)
        acc[mi][ni] = __builtin_amdgcn_mfma_f32_16x16x32_bf16(af[mi], bf[ni], acc[mi][ni], 0, 0, 0);
  }
  const int row0 = bm + wm + lk * 4;
  const int col0 = bn + wn + lrow;
#pragma unroll
  for (int mi = 0; mi < 4; ++mi)
#pragma unroll
    for (int r = 0; r < 4; ++r) {
      const int row = row0 + mi * 16 + r;
#pragma unroll
      for (int ni = 0; ni < 4; ++ni) {
        const int j = col0 + ni * 16 + row - 511;
        if (j >= 0) Sb[(size_t)row * 1024 + j] = f2b(acc[mi][ni][r] * 0.125f);
      }
    }
}

// -------- flash attention: 1D grid with XCD-coherent (n,b) grouping --------
// id = k*64 + g: the 4 i-tile blocks of group g are congruent mod 8 -> same XCD,
// so K/V (256 KB per group) stay L2-resident across the 4 blocks.
__global__ __launch_bounds__(512) void flash_attn(
    const u16* __restrict__ qkvb, const u16* __restrict__ Vt,
    const u16* __restrict__ BDs, const float* __restrict__ rwb,
    u16* __restrict__ O)
{
  __shared__ u16 qs[128][72];
  __shared__ u16 ks[2][64][72];
  __shared__ u16 vs[2][64][72];
  __shared__ u16 ps[8][16][72];
  const int id = blockIdx.x;
  const int kblk = id >> 6, g = id & 63;
  const int n = g >> 2, b = g & 3;
  const int i0 = kblk * 128;
  const int t = threadIdx.x, wave = t >> 6, lane = t & 63;
  const int lrow = lane & 15, lk = lane >> 4;
  const int ilb = wave * 16 + lk * 4;
  {
    const int qr = t >> 2, qc = (t & 3) * 16;
    const u16* qsrc = qkvb + ((size_t)(QLEN + i0 + qr) * BATCH + b) * (3 * ND) + n * 64 + qc;
#pragma unroll
    for (int p = 0; p < 2; ++p) {
      union { u16 u[8]; float4 v; } q8;
      q8.v = *(const float4*)(qsrc + p * 8);
#pragma unroll
      for (int e = 0; e < 8; ++e)
        q8.u[e] = f2b((b2f(q8.u[e]) + rwb[n * 64 + qc + p * 8 + e]) * 0.125f);
      *(float4*)&qs[qr][qc + p * 8] = q8.v;
    }
  }
  const u16* bd = BDs + ((size_t)(n * 4 + b) * QLEN + i0) * 1024;
  const int ntiles = kblk * 2 + 10;
  const int jr = t >> 3, jc = (t & 7) * 8;

  float4 kr, vr;
  u16 bdn[16], bdc[16];
  auto LOADT = [&](int j0) {
    kr = *(const float4*)(qkvb + ((size_t)(j0 + jr) * BATCH + b) * (3 * ND) + ND + n * 64 + jc);
    vr = *(const float4*)(Vt + ((size_t)(b * 16 + n) * 64 + jr) * 1024 + j0 + jc);
#pragma unroll
    for (int nf = 0; nf < 4; ++nf)
#pragma unroll
      for (int r = 0; r < 4; ++r)
        bdn[nf * 4 + r] = bd[(size_t)(ilb + r) * 1024 + j0 + nf * 16 + lrow];
  };
  auto WRITET = [&](int buf) {
    *(float4*)&ks[buf][jr][jc] = kr;
    *(float4*)&vs[buf][jr][jc] = vr;
  };

  LOADT(0);
  WRITET(0);
#pragma unroll
  for (int e = 0; e < 16; ++e) bdc[e] = bdn[e];

  f32x4 o[4] = {};
  float l[4] = {0.0f, 0.0f, 0.0f, 0.0f};

  for (int jt = 0; jt < ntiles; ++jt) {
    const int cur = jt & 1;
    const int j0 = jt * 64;
    __syncthreads();
    if (jt + 1 < ntiles) LOADT(j0 + 64);
    f32x4 s[4] = {};
    const short8 aq0 = *(const short8*)&qs[wave * 16 + lrow][lk * 8];
    const short8 aq1 = *(const short8*)&qs[wave * 16 + lrow][32 + lk * 8];
    __builtin_amdgcn_s_setprio(1);
#pragma unroll
    for (int nf = 0; nf < 4; ++nf) {
      const short8 b0 = *(const short8*)&ks[cur][nf * 16 + lrow][lk * 8];
      const short8 b1 = *(const short8*)&ks[cur][nf * 16 + lrow][32 + lk * 8];
      s[nf] = __builtin_amdgcn_mfma_f32_16x16x32_bf16(aq0, b0, s[nf], 0, 0, 0);
      s[nf] = __builtin_amdgcn_mfma_f32_16x16x32_bf16(aq1, b1, s[nf], 0, 0, 0);
    }
    __builtin_amdgcn_s_setprio(0);
    float sv[4][4];
#pragma unroll
    for (int nf = 0; nf < 4; ++nf)
#pragma unroll
      for (int r = 0; r < 4; ++r) {
        const int ig = i0 + ilb + r;
        const int jg = j0 + nf * 16 + lrow;
        const float val = s[nf][r] + b2f(bdc[nf * 4 + r]);
        sv[nf][r] = (jg <= ig + MLEN) ? __expf(val) : 0.0f;
      }
#pragma unroll
    for (int r = 0; r < 4; ++r) {
      float ls = sv[0][r] + sv[1][r] + sv[2][r] + sv[3][r];
#pragma unroll
      for (int dx = 1; dx < 16; dx <<= 1) ls += __shfl_xor(ls, dx);
      l[r] += ls;
    }
#pragma unroll
    for (int nf = 0; nf < 4; ++nf)
#pragma unroll
      for (int r = 0; r < 4; ++r)
        ps[wave][lk * 4 + r][nf * 16 + lrow] = f2b(sv[nf][r]);
    asm volatile("s_waitcnt lgkmcnt(0)" ::: "memory");
    __builtin_amdgcn_sched_barrier(0);
    const short8 pa0 = *(const short8*)&ps[wave][lrow][lk * 8];
    const short8 pa1 = *(const short8*)&ps[wave][lrow][32 + lk * 8];
    __builtin_amdgcn_s_setprio(1);
#pragma unroll
    for (int nf = 0; nf < 4; ++nf) {
      const short8 b0 = *(const short8*)&vs[cur][nf * 16 + lrow][lk * 8];
      const short8 b1 = *(const short8*)&vs[cur][nf * 16 + lrow][32 + lk * 8];
      o[nf] = __builtin_amdgcn_mfma_f32_16x16x32_bf16(pa0, b0, o[nf], 0, 0, 0);
      o[nf] = __builtin_amdgcn_mfma_f32_16x16x32_bf16(pa1, b1, o[nf], 0, 0, 0);
    }
    __builtin_amdgcn_s_setprio(0);
    if (jt + 1 < ntiles) {
      WRITET(cur ^ 1);
#pragma unroll
      for (int e = 0; e < 16; ++e) bdc[e] = bdn[e];
    }
  }
#pragma unroll
  for (int r = 0; r < 4; ++r) {
    const float inv = 1.0f / l[r];
    const size_t ig = i0 + ilb + r;
#pragma unroll
    for (int nf = 0; nf < 4; ++nf)
      O[(ig * BATCH + b) * ND + n * 64 + nf * 16 + lrow] = f2b(o[nf][r] * inv);
  }
}

// ------- fused residual + LayerNorm (optional transposed final output) -------
__global__ __launch_bounds__(256) void ln_residual_kernel(
    float* __restrict__ h, u16* __restrict__ hb,
    const u16* __restrict__ d0, const u16* __restrict__ d1,
    const float* __restrict__ g, const float* __restrict__ bb,
    float* __restrict__ outp)
{
  const int row = blockIdx.x, t = threadIdx.x;
  const int wave = t >> 6, lane = t & 63;
  __shared__ float red[8];
  const size_t ix = (size_t)row * DMODEL + t * 4;
  const float4 hv = *(const float4*)(h + ix);
  union { u16 u[4]; float2 f; } a, b2;
  a.f = *(const float2*)(d0 + ix);
  b2.f = *(const float2*)(d1 + ix);
  float x[4];
  float s = 0.0f;
#pragma unroll
  for (int e = 0; e < 4; ++e) {
    x[e] = ((const float*)&hv)[e] + b2f(a.u[e]) + b2f(b2.u[e]);
    s += x[e];
  }
#pragma unroll
  for (int dx = 32; dx > 0; dx >>= 1) s += __shfl_xor(s, dx);
  if (lane == 0) red[wave] = s;
  __syncthreads();
  const float mean = (red[0] + red[1] + red[2] + red[3]) * (1.0f / DMODEL);
  float vs = 0.0f;
#pragma unroll
  for (int e = 0; e < 4; ++e) {
    const float dv = x[e] - mean;
    vs = fmaf(dv, dv, vs);
  }
#pragma unroll
  for (int dx = 32; dx > 0; dx >>= 1) vs += __shfl_xor(vs, dx);
  if (lane == 0) red[4 + wave] = vs;
  __syncthreads();
  const float rstd = rsqrtf((red[4] + red[5] + red[6] + red[7]) * (1.0f / DMODEL) + 1e-5f);
  const float4 gv = *(const float4*)(g + t * 4);
  const float4 bv = *(const float4*)(bb + t * 4);
  float4 ho;
  union { u16 u[4]; float2 f; } po;
#pragma unroll
  for (int e = 0; e < 4; ++e) {
    const float o = (x[e] - mean) * rstd * ((const float*)&gv)[e] + ((const float*)&bv)[e];
    ((float*)&ho)[e] = o;
    po.u[e] = f2b(o);
  }
  *(float4*)(h + ix) = ho;
  *(float2*)(hb + ix) = po.f;
  if (outp != nullptr) {
    const int q = row >> 2, b = row & 3;
    *(float4*)(outp + ((size_t)b * QLEN + q) * DMODEL + t * 4) = ho;
  }
}

extern "C" void kernel_launch(void* const* d_in, const int* in_sizes, int n_in,
                              void* d_out, int out_size, void* d_ws, size_t ws_size,
                              hipStream_t stream)
{
  const int*   tok  = (const int*)d_in[0];
  const float* mems = (const float*)d_in[1];
  const float* wemb = (const float*)d_in[2];
  const float* qkvw = (const float*)d_in[3];
  const float* ow   = (const float*)d_in[4];
  const float* rw   = (const float*)d_in[5];
  const float* rwb  = (const float*)d_in[6];
  const float* rrb  = (const float*)d_in[7];
  const float* ln1g = (const float*)d_in[8];
  const float* ln1b = (const float*)d_in[9];
  const float* ffw1 = (const float*)d_in[10];
  const float* ffb1 = (const float*)d_in[11];
  const float* ffw2 = (const float*)d_in[12];
  const float* ffb2 = (const float*)d_in[13];
  const float* ln2g = (const float*)d_in[14];
  const float* ln2b = (const float*)d_in[15];

  float* h      = (float*)d_ws;               // [2048][1024] f32
  u16* S        = (u16*)(h + 2097152);        // BDshifted [64][512][1024] bf16 (64 MB)
  u16* tmp      = S;                          // alias (BD dead after flash) bf16 partial
  u16* h_bf     = S + 33554432;
  u16* qkv_bf   = h_bf + 2097152;             // [4096][3072]
  u16* ffh_bf   = qkv_bf;                     // alias (qkv dead after attention)
  u16* pe_bf    = qkv_bf + 12582912;
  u16* Vt       = pe_bf + 1048576;            // [4][16][64][1024]
  u16* vec_bf   = Vt + 4194304;               // [2048][1024]
  u16* mems_bf  = vec_bf + 2097152;           // [4][2048][1024]
  u16* wq = mems_bf + 8388608;                // [4][3072][1024]
  u16* wo = wq + 12582912;
  u16* wr = wo + 4194304;
  u16* w1 = wr + 4194304;                     // [4][4096][1024]
  u16* w2 = w1 + 16777216;                    // [4][1024][4096]
  u16* rb_all = w2 + 16777216;                // [4][1024][1024] bf16 (all layers' r)
  u16* tmp2 = rb_all + 4194304;               // [2048][1024] bf16 (split-K partial)

  // conversions + embed + posemb, one dispatch
  init_all<<<33792, 256, 0, stream>>>(
      mems, qkvw, ow, rw, ffw1, ffw2,
      mems_bf, wq, wo, wr, w1, w2,
      tok, wemb, h, h_bf, pe_bf);

  // all 4 layers' r = pe @ r_w[l]^T in one z-batched dispatch (512 blocks)
  mgemm3<2, 1, 0, 0><<<dim3(16, 8, 4), 256, 0, stream>>>(
      pe_bf, nullptr, 0, wr, rb_all, nullptr,
      1024, 1024, 1024, 1024, 1048576, 1048576);

  for (int l = 0; l < NLAYER; ++l) {
    // qkv = cat(mems_bf[l], h_bf) @ qkv_w^T  (bf16 out) — counted-vmcnt pipeline
    mgemm4<1, 0, 0><<<dim3(32, 24), 256, 0, stream>>>(
        mems_bf + (size_t)l * 2097152, h_bf, 2048,
        wq + (size_t)l * 3145728, qkv_bf, nullptr, 1024, 1024, 1024, 3072);

    // vtrans + BD GEMM, one dispatch
    attn_prep<<<3072, 256, 0, stream>>>(
        qkv_bf, rb_all + (size_t)l * 1048576, rrb + (size_t)l * ND, S, Vt);

    flash_attn<<<256, 512, 0, stream>>>(
        qkv_bf, Vt, S, rwb + (size_t)l * ND, vec_bf);

    // o-proj, split-K=2 (counted-vmcnt, bf16 partials into tmp/tmp2)
    mgemm4k<0><<<dim3(32, 8, 2), 256, 0, stream>>>(
        vec_bf, wo + (size_t)l * 1048576, tmp, tmp2, nullptr,
        512, 1024, 1024, 1024);
    ln_residual_kernel<<<2048, 256, 0, stream>>>(
        h, h_bf, tmp, tmp2, ln1g + (size_t)l * DMODEL, ln1b + (size_t)l * DMODEL,
        nullptr);
    // FFN1 (bf16 out, bias+relu) — counted-vmcnt pipeline
    mgemm4<1, 1, 1><<<dim3(16, 32), 256, 0, stream>>>(
        h_bf, nullptr, 0, w1 + (size_t)l * 4194304, ffh_bf,
        ffb1 + (size_t)l * DINNER, 1024, 1024, 1024, 4096);
    // FFN2, split-K=2 (counted-vmcnt, bf16 partials, bias in z=0)
    mgemm4k<1><<<dim3(32, 8, 2), 256, 0, stream>>>(
        ffh_bf, w2 + (size_t)l * 4194304, tmp, tmp2,
        ffb2 + (size_t)l * DMODEL, 2048, 4096, 4096, 1024);
    ln_residual_kernel<<<2048, 256, 0, stream>>>(
        h, h_bf, tmp, tmp2, ln2g + (size_t)l * DMODEL, ln2b + (size_t)l * DMODEL,
        (l == NLAYER - 1) ? (float*)d_out : nullptr);
  }
}

// Round 21
// 784.713 us; speedup vs baseline: 1.0116x; 1.0116x over previous
//
#include <hip/hip_runtime.h>
#include <cstdint>

#define NLAYER 4
#define DMODEL 1024
#define NHEAD 16
#define DHEAD 64
#define DINNER 4096
#define QLEN 512
#define MLEN 512
#define KLEN (QLEN + MLEN)
#define BATCH 4
#define ND (NHEAD * DHEAD)

typedef unsigned short u16;
typedef __attribute__((ext_vector_type(8))) short short8;
typedef __attribute__((ext_vector_type(4))) float f32x4;
typedef __attribute__((address_space(1))) const unsigned int guint;
typedef __attribute__((address_space(3))) unsigned int luint;

__device__ __forceinline__ u16 f2b(float x) {
  unsigned u = __builtin_bit_cast(unsigned, x);
  return (u16)((u + 0x7fffu + ((u >> 16) & 1u)) >> 16);
}
__device__ __forceinline__ float b2f(u16 h) {
  return __builtin_bit_cast(float, (unsigned)h << 16);
}

// ======== init_all: conversions (non-temporal) + embedding + pos-emb ========
// conv blocks [0,30720); [30720,32768): embed; [32768,33792): posemb
__global__ __launch_bounds__(256) void init_all(
    const float* __restrict__ s0, const float* __restrict__ s1,
    const float* __restrict__ s2, const float* __restrict__ s3,
    const float* __restrict__ s4, const float* __restrict__ s5,
    u16* __restrict__ d0, u16* __restrict__ d1, u16* __restrict__ d2,
    u16* __restrict__ d3, u16* __restrict__ d4, u16* __restrict__ d5,
    const int* __restrict__ tok, const float* __restrict__ emb,
    float* __restrict__ h, u16* __restrict__ hb, u16* __restrict__ pe)
{
  const int blk = blockIdx.x;
  const int t = threadIdx.x;
  if (blk < 30720) {
    int i = blk * 256 + t;
    const float* s; u16* d;
    if      (i < 1048576) { s = s0; d = d0; }
    else if (i < 2621440) { s = s1; d = d1; i -= 1048576; }
    else if (i < 3145728) { s = s2; d = d2; i -= 2621440; }
    else if (i < 3670016) { s = s3; d = d3; i -= 3145728; }
    else if (i < 5767168) { s = s4; d = d4; i -= 3670016; }
    else                  { s = s5; d = d5; i -= 5767168; }
    const f32x4 a = __builtin_nontemporal_load((const f32x4*)s + 2 * i);
    const f32x4 b = __builtin_nontemporal_load((const f32x4*)s + 2 * i + 1);
    union { u16 u[8]; f32x4 v; } p;
    p.u[0] = f2b(a.x); p.u[1] = f2b(a.y); p.u[2] = f2b(a.z); p.u[3] = f2b(a.w);
    p.u[4] = f2b(b.x); p.u[5] = f2b(b.y); p.u[6] = f2b(b.z); p.u[7] = f2b(b.w);
    __builtin_nontemporal_store(p.v, (f32x4*)d + i);
  } else if (blk < 32768) {
    const int e = blk - 30720;
    const int q = e >> 2, b = e & 3;
    const int id = tok[b * QLEN + q];
    const float4 v = ((const float4*)(emb + (size_t)id * DMODEL))[t];
    const size_t row = (size_t)q * BATCH + b;
    ((float4*)(h + row * DMODEL))[t] = v;
    union { u16 u[4]; float2 f; } p;
    p.u[0] = f2b(v.x); p.u[1] = f2b(v.y); p.u[2] = f2b(v.z); p.u[3] = f2b(v.w);
    *(float2*)(hb + row * DMODEL + t * 4) = p.f;
  } else {
    const int k = blk - 32768;
    const float pos = (float)(KLEN - 1 - k);
    for (int i = t; i < DMODEL / 2; i += 256) {
      const float inv_freq = powf(10000.0f, -(float)(2 * i) / (float)DMODEL);
      const float a = pos * inv_freq;
      pe[(size_t)k * DMODEL + i] = f2b(sinf(a));
      pe[(size_t)k * DMODEL + DMODEL / 2 + i] = f2b(cosf(a));
    }
  }
}

// ======== mgemm4: counted vmcnt(8) + raw double barrier + setprio (MF=4) ========
template<int OUTBF, int RELU, int BIAS>
__global__ __launch_bounds__(256) void mgemm4(
    const u16* __restrict__ A0, const u16* __restrict__ A1, int splitRow,
    const u16* __restrict__ B, void* __restrict__ Cp,
    const float* __restrict__ bias, int Kd, long sa, long sb, long sc)
{
  constexpr int MF = 4;
  constexpr int BM = 128;
  constexpr int NGA = 16;
  constexpr int GPW = 8;
  __shared__ u16 As[2][BM][64];
  __shared__ u16 Bs[2][128][64];
  const int nwg = gridDim.x * gridDim.y;
  int wg = blockIdx.y * gridDim.x + blockIdx.x;
  wg = (wg & 7) * (nwg >> 3) + (wg >> 3);
  const int bm = (wg % gridDim.x) * BM;
  const int bn = (wg / gridDim.x) * 128;
  const int t = threadIdx.x, wave = t >> 6, lane = t & 63;
  const int wm = (wave >> 1) * (MF * 16), wn = (wave & 1) * 64;
  const int lrow = lane & 15, lk = lane >> 4;
  const int gsw = ((lane & 7) ^ (lane >> 3)) * 8;
  const u16* gptr[GPW];
  int row8[GPW];
  bool isA[GPW];
#pragma unroll
  for (int c = 0; c < GPW; ++c) {
    const int g = wave * GPW + c;
    isA[c] = g < NGA;
    row8[c] = (isA[c] ? g : g - NGA) * 8;
    const int row = row8[c] + (lane >> 3);
    if (isA[c]) {
      const int ga = bm + row;
      gptr[c] = ((A1 != nullptr && ga >= splitRow)
                     ? A1 + (size_t)(ga - splitRow) * sa
                     : A0 + (size_t)ga * sa) + gsw;
    } else {
      gptr[c] = B + (size_t)(bn + row) * sb + gsw;
    }
  }
  auto STAGE = [&](int buf, int k0) {
#pragma unroll
    for (int c = 0; c < GPW; ++c) {
      luint* dst = isA[c] ? (luint*)&As[buf][row8[c]][0] : (luint*)&Bs[buf][row8[c]][0];
      __builtin_amdgcn_global_load_lds((guint*)(gptr[c] + k0), dst, 16, 0, 0);
    }
  };
  f32x4 acc[MF][4] = {};
  const int nt = Kd >> 6;
  STAGE(0, 0);
  for (int ti = 0; ti < nt; ++ti) {
    const int cur = ti & 1;
    if (ti + 1 < nt) {
      STAGE(cur ^ 1, (ti + 1) << 6);
      asm volatile("s_waitcnt vmcnt(8)" ::: "memory");
    } else {
      asm volatile("s_waitcnt vmcnt(0)" ::: "memory");
    }
    __builtin_amdgcn_s_barrier();
    __builtin_amdgcn_sched_barrier(0);
    __builtin_amdgcn_s_setprio(1);
#pragma unroll
    for (int ks = 0; ks < 2; ++ks) {
      short8 af[MF], bf[4];
#pragma unroll
      for (int x = 0; x < MF; ++x) {
        const int ra = wm + x * 16 + lrow;
        af[x] = *(const short8*)((const u16*)&As[cur][0][0] + ra * 64 + (((ks * 4 + lk) ^ (ra & 7)) * 8));
      }
#pragma unroll
      for (int x = 0; x < 4; ++x) {
        const int rb = wn + x * 16 + lrow;
        bf[x] = *(const short8*)((const u16*)&Bs[cur][0][0] + rb * 64 + (((ks * 4 + lk) ^ (rb & 7)) * 8));
      }
#pragma unroll
      for (int mi = 0; mi < MF; ++mi)
#pragma unroll
        for (int ni = 0; ni < 4; ++ni)
          acc[mi][ni] = __builtin_amdgcn_mfma_f32_16x16x32_bf16(af[mi], bf[ni], acc[mi][ni], 0, 0, 0);
    }
    __builtin_amdgcn_s_setprio(0);
    asm volatile("s_waitcnt lgkmcnt(0)" ::: "memory");
    __builtin_amdgcn_s_barrier();
    __builtin_amdgcn_sched_barrier(0);
  }
  const size_t row0 = bm + wm + lk * 4;
  const size_t col0 = bn + wn + lrow;
#pragma unroll
  for (int mi = 0; mi < MF; ++mi)
#pragma unroll
    for (int r = 0; r < 4; ++r) {
      const size_t row = row0 + mi * 16 + r;
#pragma unroll
      for (int ni = 0; ni < 4; ++ni) {
        float v = acc[mi][ni][r];
        if (BIAS) v += bias[col0 + ni * 16];
        if (RELU) v = fmaxf(v, 0.0f);
        if (OUTBF) ((u16*)Cp)[row * sc + col0 + ni * 16] = f2b(v);
        else       ((float*)Cp)[row * sc + col0 + ni * 16] = v;
      }
    }
}

// ======== mgemm4k: split-K=2, MF=2, counted vmcnt(6) + setprio, bf16 partials ========
template<int BIAS>
__global__ __launch_bounds__(256) void mgemm4k(
    const u16* __restrict__ A, const u16* __restrict__ B,
    u16* __restrict__ C0, u16* __restrict__ C1,
    const float* __restrict__ bias, int KdH, long sa, long sb, long sc)
{
  constexpr int MF = 2;
  constexpr int BM = 64;
  constexpr int NGA = 8;
  constexpr int GPW = 6;
  __shared__ u16 As[2][BM][64];
  __shared__ u16 Bs[2][128][64];
  const int z = blockIdx.z;
  A += (size_t)z * KdH;
  B += (size_t)z * KdH;
  u16* C = z ? C1 : C0;
  const int nwg = gridDim.x * gridDim.y;
  int wg = blockIdx.y * gridDim.x + blockIdx.x;
  wg = (wg & 7) * (nwg >> 3) + (wg >> 3);
  const int bm = (wg % gridDim.x) * BM;
  const int bn = (wg / gridDim.x) * 128;
  const int t = threadIdx.x, wave = t >> 6, lane = t & 63;
  const int wm = (wave >> 1) * (MF * 16), wn = (wave & 1) * 64;
  const int lrow = lane & 15, lk = lane >> 4;
  const int gsw = ((lane & 7) ^ (lane >> 3)) * 8;
  const u16* gptr[GPW];
  int row8[GPW];
  bool isA[GPW];
#pragma unroll
  for (int c = 0; c < GPW; ++c) {
    const int g = wave * GPW + c;
    isA[c] = g < NGA;
    row8[c] = (isA[c] ? g : g - NGA) * 8;
    const int row = row8[c] + (lane >> 3);
    gptr[c] = isA[c] ? A + (size_t)(bm + row) * sa + gsw
                     : B + (size_t)(bn + row) * sb + gsw;
  }
  auto STAGE = [&](int buf, int k0) {
#pragma unroll
    for (int c = 0; c < GPW; ++c) {
      luint* dst = isA[c] ? (luint*)&As[buf][row8[c]][0] : (luint*)&Bs[buf][row8[c]][0];
      __builtin_amdgcn_global_load_lds((guint*)(gptr[c] + k0), dst, 16, 0, 0);
    }
  };
  f32x4 acc[MF][4] = {};
  const int nt = KdH >> 6;
  STAGE(0, 0);
  for (int ti = 0; ti < nt; ++ti) {
    const int cur = ti & 1;
    if (ti + 1 < nt) {
      STAGE(cur ^ 1, (ti + 1) << 6);
      asm volatile("s_waitcnt vmcnt(6)" ::: "memory");
    } else {
      asm volatile("s_waitcnt vmcnt(0)" ::: "memory");
    }
    __builtin_amdgcn_s_barrier();
    __builtin_amdgcn_sched_barrier(0);
    __builtin_amdgcn_s_setprio(1);
#pragma unroll
    for (int ks = 0; ks < 2; ++ks) {
      short8 af[MF], bf[4];
#pragma unroll
      for (int x = 0; x < MF; ++x) {
        const int ra = wm + x * 16 + lrow;
        af[x] = *(const short8*)((const u16*)&As[cur][0][0] + ra * 64 + (((ks * 4 + lk) ^ (ra & 7)) * 8));
      }
#pragma unroll
      for (int x = 0; x < 4; ++x) {
        const int rb = wn + x * 16 + lrow;
        bf[x] = *(const short8*)((const u16*)&Bs[cur][0][0] + rb * 64 + (((ks * 4 + lk) ^ (rb & 7)) * 8));
      }
#pragma unroll
      for (int mi = 0; mi < MF; ++mi)
#pragma unroll
        for (int ni = 0; ni < 4; ++ni)
          acc[mi][ni] = __builtin_amdgcn_mfma_f32_16x16x32_bf16(af[mi], bf[ni], acc[mi][ni], 0, 0, 0);
    }
    __builtin_amdgcn_s_setprio(0);
    asm volatile("s_waitcnt lgkmcnt(0)" ::: "memory");
    __builtin_amdgcn_s_barrier();
    __builtin_amdgcn_sched_barrier(0);
  }
  const size_t row0 = bm + wm + lk * 4;
  const size_t col0 = bn + wn + lrow;
#pragma unroll
  for (int mi = 0; mi < MF; ++mi)
#pragma unroll
    for (int r = 0; r < 4; ++r) {
      const size_t row = row0 + mi * 16 + r;
#pragma unroll
      for (int ni = 0; ni < 4; ++ni) {
        float v = acc[mi][ni][r];
        if (BIAS && z == 0) v += bias[col0 + ni * 16];
        C[row * sc + col0 + ni * 16] = f2b(v);
      }
    }
}

// ======== mgemm3: 2-phase double-buffered NT GEMM (validated; r GEMM) ========
template<int MF, int OUTBF, int RELU, int BIAS>
__global__ __launch_bounds__(256) void mgemm3(
    const u16* __restrict__ A0, const u16* __restrict__ A1, int splitRow,
    const u16* __restrict__ B, void* __restrict__ Cp,
    const float* __restrict__ bias, int Kd, long sa, long sb, long sc,
    long bzs, long czs)
{
  constexpr int BM = MF * 32;
  constexpr int NGA = BM / 8;
  constexpr int GPW = (NGA + 16) / 4;
  __shared__ u16 As[2][BM][64];
  __shared__ u16 Bs[2][128][64];
  const int zz = blockIdx.z;
  B += (size_t)zz * bzs;
  const int nwg = gridDim.x * gridDim.y;
  int wg = blockIdx.y * gridDim.x + blockIdx.x;
  wg = (wg & 7) * (nwg >> 3) + (wg >> 3);
  const int bm = (wg % gridDim.x) * BM;
  const int bn = (wg / gridDim.x) * 128;
  const int t = threadIdx.x, wave = t >> 6, lane = t & 63;
  const int wm = (wave >> 1) * (MF * 16), wn = (wave & 1) * 64;
  const int lrow = lane & 15, lk = lane >> 4;
  const int gsw = ((lane & 7) ^ (lane >> 3)) * 8;
  const u16* gptr[GPW];
  int row8[GPW];
  bool isA[GPW];
#pragma unroll
  for (int c = 0; c < GPW; ++c) {
    const int g = wave * GPW + c;
    isA[c] = g < NGA;
    row8[c] = (isA[c] ? g : g - NGA) * 8;
    const int row = row8[c] + (lane >> 3);
    if (isA[c]) {
      const int ga = bm + row;
      gptr[c] = ((A1 != nullptr && ga >= splitRow)
                     ? A1 + (size_t)(ga - splitRow) * sa
                     : A0 + (size_t)ga * sa) + gsw;
    } else {
      gptr[c] = B + (size_t)(bn + row) * sb + gsw;
    }
  }
  auto STAGE = [&](int buf, int k0) {
#pragma unroll
    for (int c = 0; c < GPW; ++c) {
      luint* dst = isA[c] ? (luint*)&As[buf][row8[c]][0] : (luint*)&Bs[buf][row8[c]][0];
      __builtin_amdgcn_global_load_lds((guint*)(gptr[c] + k0), dst, 16, 0, 0);
    }
  };
  f32x4 acc[MF][4] = {};
  const int nt = Kd >> 6;
  STAGE(0, 0);
  __syncthreads();
  for (int ti = 0; ti < nt; ++ti) {
    const int cur = ti & 1;
    if (ti + 1 < nt) STAGE(cur ^ 1, (ti + 1) << 6);
#pragma unroll
    for (int ks = 0; ks < 2; ++ks) {
      short8 af[MF], bf[4];
#pragma unroll
      for (int x = 0; x < MF; ++x) {
        const int ra = wm + x * 16 + lrow;
        af[x] = *(const short8*)((const u16*)&As[cur][0][0] + ra * 64 + (((ks * 4 + lk) ^ (ra & 7)) * 8));
      }
#pragma unroll
      for (int x = 0; x < 4; ++x) {
        const int rb = wn + x * 16 + lrow;
        bf[x] = *(const short8*)((const u16*)&Bs[cur][0][0] + rb * 64 + (((ks * 4 + lk) ^ (rb & 7)) * 8));
      }
#pragma unroll
      for (int mi = 0; mi < MF; ++mi)
#pragma unroll
        for (int ni = 0; ni < 4; ++ni)
          acc[mi][ni] = __builtin_amdgcn_mfma_f32_16x16x32_bf16(af[mi], bf[ni], acc[mi][ni], 0, 0, 0);
    }
    __syncthreads();
  }
  const size_t row0 = bm + wm + lk * 4;
  const size_t col0 = bn + wn + lrow;
#pragma unroll
  for (int mi = 0; mi < MF; ++mi)
#pragma unroll
    for (int r = 0; r < 4; ++r) {
      const size_t row = row0 + mi * 16 + r;
#pragma unroll
      for (int ni = 0; ni < 4; ++ni) {
        float v = acc[mi][ni][r];
        if (BIAS) v += bias[col0 + ni * 16];
        if (RELU) v = fmaxf(v, 0.0f);
        if (OUTBF) ((u16*)Cp + (size_t)zz * czs)[row * sc + col0 + ni * 16] = f2b(v);
        else       ((float*)Cp + (size_t)zz * czs)[row * sc + col0 + ni * 16] = v;
      }
    }
}

// ======== attn_prep: vtrans + bd_gemm in ONE dispatch (block ranges) ========
__global__ __launch_bounds__(256) void attn_prep(
    const u16* __restrict__ qkvb, const u16* __restrict__ rb,
    const float* __restrict__ rrb, u16* __restrict__ S, u16* __restrict__ Vt)
{
  __shared__ u16 sh[2 * 128 * 72];
  const int idx = blockIdx.x;
  const int t = threadIdx.x;
  if (idx < 1024) {
    u16 (*T)[72] = (u16(*)[72])sh;
    const int j0 = (idx & 15) * 64;
    const int bn = idx >> 4, b = bn >> 4, n = bn & 15;
    const int jl = t >> 3, ch = t & 7;
#pragma unroll
    for (int p = 0; p < 2; ++p) {
      const int jj = p * 32 + jl;
      const float4 v = *(const float4*)(qkvb + ((size_t)(j0 + jj) * BATCH + b) * (3 * ND)
                                        + 2 * ND + n * 64 + ch * 8);
      *(float4*)&T[jj][ch * 8] = v;
    }
    __syncthreads();
#pragma unroll
    for (int p = 0; p < 2; ++p) {
      const int dd = p * 32 + jl;
      union { u16 u[8]; float4 v; } o;
#pragma unroll
      for (int e = 0; e < 8; ++e) o.u[e] = T[ch * 8 + e][dd];
      *(float4*)(Vt + ((size_t)(b * 16 + n) * 64 + dd) * 1024 + j0 + ch * 8) = o.v;
    }
    return;
  }
  const int i2 = idx - 1024;
  const int bm = (i2 & 3) * 128, bn = ((i2 >> 2) & 7) * 128;
  if (bm + bn < 257) return;
  const int z = i2 >> 5, zb = z & 3, zn = z >> 2;
  u16 (*As)[72] = (u16(*)[72])sh;
  u16 (*Bs)[72] = (u16(*)[72])(sh + 128 * 72);
  const u16* Ab = qkvb + ((size_t)(QLEN * BATCH) + zb) * (3 * ND) + zn * 64;
  const u16* Bb = rb + zn * 64;
  u16* Sb = S + (size_t)(zn * 4 + zb) * 524288;
  const int wave = t >> 6, lane = t & 63;
  const int wm = (wave >> 1) * 64, wn = (wave & 1) * 64;
  const int lrow = lane & 15, lk = lane >> 4;
  const int sr = t >> 2, sc = (t & 3) * 16;
#pragma unroll
  for (int p = 0; p < 2; ++p) {
    const int row = sr + p * 64;
    union { u16 u[16]; float4 v[2]; } av;
    av.v[0] = *(const float4*)(Ab + (size_t)(bm + row) * (BATCH * 3 * ND) + sc);
    av.v[1] = *(const float4*)(Ab + (size_t)(bm + row) * (BATCH * 3 * ND) + sc + 8);
#pragma unroll
    for (int e = 0; e < 16; ++e) av.u[e] = f2b(b2f(av.u[e]) + rrb[zn * 64 + sc + e]);
    *(float4*)&As[row][sc] = av.v[0];
    *(float4*)&As[row][sc + 8] = av.v[1];
    const float4 b0 = *(const float4*)(Bb + (size_t)(bn + row) * 1024 + sc);
    const float4 b1 = *(const float4*)(Bb + (size_t)(bn + row) * 1024 + sc + 8);
    *(float4*)&Bs[row][sc] = b0;
    *(float4*)&Bs[row][sc + 8] = b1;
  }
  __syncthreads();
  f32x4 acc[4][4] = {};
#pragma unroll
  for (int ks = 0; ks < 2; ++ks) {
    short8 af[4], bf[4];
#pragma unroll
    for (int x = 0; x < 4; ++x) af[x] = *(const short8*)&As[wm + x * 16 + lrow][ks * 32 + lk * 8];
#pragma unroll
    for (int x = 0; x < 4; ++x) bf[x] = *(const short8*)&Bs[wn + x * 16 + lrow][ks * 32 + lk * 8];
#pragma unroll
    for (int mi = 0; mi < 4; ++mi)
#pragma unroll
      for (int ni = 0; ni < 4; ++ni)
        acc[mi][ni] = __builtin_amdgcn_mfma_f32_16x16x32_bf16(af[mi], bf[ni], acc[mi][ni], 0, 0, 0);
  }
  const int row0 = bm + wm + lk * 4;
  const int col0 = bn + wn + lrow;
#pragma unroll
  for (int mi = 0; mi < 4; ++mi)
#pragma unroll
    for (int r = 0; r < 4; ++r) {
      const int row = row0 + mi * 16 + r;
#pragma unroll
      for (int ni = 0; ni < 4; ++ni) {
        const int j = col0 + ni * 16 + row - 511;
        if (j >= 0) Sb[(size_t)row * 1024 + j] = f2b(acc[mi][ni][r] * 0.125f);
      }
    }
}

// -------- flash attention: 1D grid with XCD-coherent (n,b) grouping --------
__global__ __launch_bounds__(512) void flash_attn(
    const u16* __restrict__ qkvb, const u16* __restrict__ Vt,
    const u16* __restrict__ BDs, const float* __restrict__ rwb,
    u16* __restrict__ O)
{
  __shared__ u16 qs[128][72];
  __shared__ u16 ks[2][64][72];
  __shared__ u16 vs[2][64][72];
  __shared__ u16 ps[8][16][72];
  const int id = blockIdx.x;
  const int kblk = id >> 6, g = id & 63;
  const int n = g >> 2, b = g & 3;
  const int i0 = kblk * 128;
  const int t = threadIdx.x, wave = t >> 6, lane = t & 63;
  const int lrow = lane & 15, lk = lane >> 4;
  const int ilb = wave * 16 + lk * 4;
  {
    const int qr = t >> 2, qc = (t & 3) * 16;
    const u16* qsrc = qkvb + ((size_t)(QLEN + i0 + qr) * BATCH + b) * (3 * ND) + n * 64 + qc;
#pragma unroll
    for (int p = 0; p < 2; ++p) {
      union { u16 u[8]; float4 v; } q8;
      q8.v = *(const float4*)(qsrc + p * 8);
#pragma unroll
      for (int e = 0; e < 8; ++e)
        q8.u[e] = f2b((b2f(q8.u[e]) + rwb[n * 64 + qc + p * 8 + e]) * 0.125f);
      *(float4*)&qs[qr][qc + p * 8] = q8.v;
    }
  }
  const u16* bd = BDs + ((size_t)(n * 4 + b) * QLEN + i0) * 1024;
  const int ntiles = kblk * 2 + 10;
  const int jr = t >> 3, jc = (t & 7) * 8;

  float4 kr, vr;
  u16 bdn[16], bdc[16];
  auto LOADT = [&](int j0) {
    kr = *(const float4*)(qkvb + ((size_t)(j0 + jr) * BATCH + b) * (3 * ND) + ND + n * 64 + jc);
    vr = *(const float4*)(Vt + ((size_t)(b * 16 + n) * 64 + jr) * 1024 + j0 + jc);
#pragma unroll
    for (int nf = 0; nf < 4; ++nf)
#pragma unroll
      for (int r = 0; r < 4; ++r)
        bdn[nf * 4 + r] = bd[(size_t)(ilb + r) * 1024 + j0 + nf * 16 + lrow];
  };
  auto WRITET = [&](int buf) {
    *(float4*)&ks[buf][jr][jc] = kr;
    *(float4*)&vs[buf][jr][jc] = vr;
  };

  LOADT(0);
  WRITET(0);
#pragma unroll
  for (int e = 0; e < 16; ++e) bdc[e] = bdn[e];

  f32x4 o[4] = {};
  float l[4] = {0.0f, 0.0f, 0.0f, 0.0f};

  for (int jt = 0; jt < ntiles; ++jt) {
    const int cur = jt & 1;
    const int j0 = jt * 64;
    __syncthreads();
    if (jt + 1 < ntiles) LOADT(j0 + 64);
    f32x4 s[4] = {};
    const short8 aq0 = *(const short8*)&qs[wave * 16 + lrow][lk * 8];
    const short8 aq1 = *(const short8*)&qs[wave * 16 + lrow][32 + lk * 8];
    __builtin_amdgcn_s_setprio(1);
#pragma unroll
    for (int nf = 0; nf < 4; ++nf) {
      const short8 b0 = *(const short8*)&ks[cur][nf * 16 + lrow][lk * 8];
      const short8 b1 = *(const short8*)&ks[cur][nf * 16 + lrow][32 + lk * 8];
      s[nf] = __builtin_amdgcn_mfma_f32_16x16x32_bf16(aq0, b0, s[nf], 0, 0, 0);
      s[nf] = __builtin_amdgcn_mfma_f32_16x16x32_bf16(aq1, b1, s[nf], 0, 0, 0);
    }
    __builtin_amdgcn_s_setprio(0);
    float sv[4][4];
#pragma unroll
    for (int nf = 0; nf < 4; ++nf)
#pragma unroll
      for (int r = 0; r < 4; ++r) {
        const int ig = i0 + ilb + r;
        const int jg = j0 + nf * 16 + lrow;
        const float val = s[nf][r] + b2f(bdc[nf * 4 + r]);
        sv[nf][r] = (jg <= ig + MLEN) ? __expf(val) : 0.0f;
      }
#pragma unroll
    for (int r = 0; r < 4; ++r) {
      float ls = sv[0][r] + sv[1][r] + sv[2][r] + sv[3][r];
#pragma unroll
      for (int dx = 1; dx < 16; dx <<= 1) ls += __shfl_xor(ls, dx);
      l[r] += ls;
    }
#pragma unroll
    for (int nf = 0; nf < 4; ++nf)
#pragma unroll
      for (int r = 0; r < 4; ++r)
        ps[wave][lk * 4 + r][nf * 16 + lrow] = f2b(sv[nf][r]);
    asm volatile("s_waitcnt lgkmcnt(0)" ::: "memory");
    __builtin_amdgcn_sched_barrier(0);
    const short8 pa0 = *(const short8*)&ps[wave][lrow][lk * 8];
    const short8 pa1 = *(const short8*)&ps[wave][lrow][32 + lk * 8];
    __builtin_amdgcn_s_setprio(1);
#pragma unroll
    for (int nf = 0; nf < 4; ++nf) {
      const short8 b0 = *(const short8*)&vs[cur][nf * 16 + lrow][lk * 8];
      const short8 b1 = *(const short8*)&vs[cur][nf * 16 + lrow][32 + lk * 8];
      o[nf] = __builtin_amdgcn_mfma_f32_16x16x32_bf16(pa0, b0, o[nf], 0, 0, 0);
      o[nf] = __builtin_amdgcn_mfma_f32_16x16x32_bf16(pa1, b1, o[nf], 0, 0, 0);
    }
    __builtin_amdgcn_s_setprio(0);
    if (jt + 1 < ntiles) {
      WRITET(cur ^ 1);
#pragma unroll
      for (int e = 0; e < 16; ++e) bdc[e] = bdn[e];
    }
  }
#pragma unroll
  for (int r = 0; r < 4; ++r) {
    const float inv = 1.0f / l[r];
    const size_t ig = i0 + ilb + r;
#pragma unroll
    for (int nf = 0; nf < 4; ++nf)
      O[(ig * BATCH + b) * ND + n * 64 + nf * 16 + lrow] = f2b(o[nf][r] * inv);
  }
}

// ------- fused residual + LayerNorm (optional transposed final output) -------
__global__ __launch_bounds__(256) void ln_residual_kernel(
    float* __restrict__ h, u16* __restrict__ hb,
    const u16* __restrict__ d0, const u16* __restrict__ d1,
    const float* __restrict__ g, const float* __restrict__ bb,
    float* __restrict__ outp)
{
  const int row = blockIdx.x, t = threadIdx.x;
  const int wave = t >> 6, lane = t & 63;
  __shared__ float red[8];
  const size_t ix = (size_t)row * DMODEL + t * 4;
  const float4 hv = *(const float4*)(h + ix);
  union { u16 u[4]; float2 f; } a, b2;
  a.f = *(const float2*)(d0 + ix);
  b2.f = *(const float2*)(d1 + ix);
  float x[4];
  float s = 0.0f;
#pragma unroll
  for (int e = 0; e < 4; ++e) {
    x[e] = ((const float*)&hv)[e] + b2f(a.u[e]) + b2f(b2.u[e]);
    s += x[e];
  }
#pragma unroll
  for (int dx = 32; dx > 0; dx >>= 1) s += __shfl_xor(s, dx);
  if (lane == 0) red[wave] = s;
  __syncthreads();
  const float mean = (red[0] + red[1] + red[2] + red[3]) * (1.0f / DMODEL);
  float vs = 0.0f;
#pragma unroll
  for (int e = 0; e < 4; ++e) {
    const float dv = x[e] - mean;
    vs = fmaf(dv, dv, vs);
  }
#pragma unroll
  for (int dx = 32; dx > 0; dx >>= 1) vs += __shfl_xor(vs, dx);
  if (lane == 0) red[4 + wave] = vs;
  __syncthreads();
  const float rstd = rsqrtf((red[4] + red[5] + red[6] + red[7]) * (1.0f / DMODEL) + 1e-5f);
  const float4 gv = *(const float4*)(g + t * 4);
  const float4 bv = *(const float4*)(bb + t * 4);
  float4 ho;
  union { u16 u[4]; float2 f; } po;
#pragma unroll
  for (int e = 0; e < 4; ++e) {
    const float o = (x[e] - mean) * rstd * ((const float*)&gv)[e] + ((const float*)&bv)[e];
    ((float*)&ho)[e] = o;
    po.u[e] = f2b(o);
  }
  *(float4*)(h + ix) = ho;
  *(float2*)(hb + ix) = po.f;
  if (outp != nullptr) {
    const int q = row >> 2, b = row & 3;
    *(float4*)(outp + ((size_t)b * QLEN + q) * DMODEL + t * 4) = ho;
  }
}

extern "C" void kernel_launch(void* const* d_in, const int* in_sizes, int n_in,
                              void* d_out, int out_size, void* d_ws, size_t ws_size,
                              hipStream_t stream)
{
  const int*   tok  = (const int*)d_in[0];
  const float* mems = (const float*)d_in[1];
  const float* wemb = (const float*)d_in[2];
  const float* qkvw = (const float*)d_in[3];
  const float* ow   = (const float*)d_in[4];
  const float* rw   = (const float*)d_in[5];
  const float* rwb  = (const float*)d_in[6];
  const float* rrb  = (const float*)d_in[7];
  const float* ln1g = (const float*)d_in[8];
  const float* ln1b = (const float*)d_in[9];
  const float* ffw1 = (const float*)d_in[10];
  const float* ffb1 = (const float*)d_in[11];
  const float* ffw2 = (const float*)d_in[12];
  const float* ffb2 = (const float*)d_in[13];
  const float* ln2g = (const float*)d_in[14];
  const float* ln2b = (const float*)d_in[15];

  float* h      = (float*)d_ws;               // [2048][1024] f32
  u16* S        = (u16*)(h + 2097152);        // BDshifted [64][512][1024] bf16 (64 MB)
  u16* tmp      = S;                          // alias (BD dead after flash) bf16 partial
  u16* h_bf     = S + 33554432;
  u16* qkv_bf   = h_bf + 2097152;             // [4096][3072]
  u16* ffh_bf   = qkv_bf;                     // alias (qkv dead after attention)
  u16* pe_bf    = qkv_bf + 12582912;
  u16* Vt       = pe_bf + 1048576;            // [4][16][64][1024]
  u16* vec_bf   = Vt + 4194304;               // [2048][1024]
  u16* mems_bf  = vec_bf + 2097152;           // [4][2048][1024]
  u16* wq = mems_bf + 8388608;                // [4][3072][1024]
  u16* wo = wq + 12582912;
  u16* wr = wo + 4194304;
  u16* w1 = wr + 4194304;                     // [4][4096][1024]
  u16* w2 = w1 + 16777216;                    // [4][1024][4096]
  u16* rb_all = w2 + 16777216;                // [4][1024][1024] bf16 (all layers' r)
  u16* tmp2 = rb_all + 4194304;               // [2048][1024] bf16 (split-K partial)

  // conversions (non-temporal) + embed + posemb, one dispatch
  init_all<<<33792, 256, 0, stream>>>(
      mems, qkvw, ow, rw, ffw1, ffw2,
      mems_bf, wq, wo, wr, w1, w2,
      tok, wemb, h, h_bf, pe_bf);

  // all 4 layers' r = pe @ r_w[l]^T in one z-batched dispatch (512 blocks)
  mgemm3<2, 1, 0, 0><<<dim3(16, 8, 4), 256, 0, stream>>>(
      pe_bf, nullptr, 0, wr, rb_all, nullptr,
      1024, 1024, 1024, 1024, 1048576, 1048576);

  for (int l = 0; l < NLAYER; ++l) {
    // qkv = cat(mems_bf[l], h_bf) @ qkv_w^T  (bf16 out) — counted-vmcnt pipeline
    mgemm4<1, 0, 0><<<dim3(32, 24), 256, 0, stream>>>(
        mems_bf + (size_t)l * 2097152, h_bf, 2048,
        wq + (size_t)l * 3145728, qkv_bf, nullptr, 1024, 1024, 1024, 3072);

    // vtrans + BD GEMM, one dispatch
    attn_prep<<<3072, 256, 0, stream>>>(
        qkv_bf, rb_all + (size_t)l * 1048576, rrb + (size_t)l * ND, S, Vt);

    flash_attn<<<256, 512, 0, stream>>>(
        qkv_bf, Vt, S, rwb + (size_t)l * ND, vec_bf);

    // o-proj, split-K=2 (counted-vmcnt, bf16 partials into tmp/tmp2)
    mgemm4k<0><<<dim3(32, 8, 2), 256, 0, stream>>>(
        vec_bf, wo + (size_t)l * 1048576, tmp, tmp2, nullptr,
        512, 1024, 1024, 1024);
    ln_residual_kernel<<<2048, 256, 0, stream>>>(
        h, h_bf, tmp, tmp2, ln1g + (size_t)l * DMODEL, ln1b + (size_t)l * DMODEL,
        nullptr);
    // FFN1 (bf16 out, bias+relu) — counted-vmcnt pipeline
    mgemm4<1, 1, 1><<<dim3(16, 32), 256, 0, stream>>>(
        h_bf, nullptr, 0, w1 + (size_t)l * 4194304, ffh_bf,
        ffb1 + (size_t)l * DINNER, 1024, 1024, 1024, 4096);
    // FFN2, split-K=2 (counted-vmcnt, bf16 partials, bias in z=0)
    mgemm4k<1><<<dim3(32, 8, 2), 256, 0, stream>>>(
        ffh_bf, w2 + (size_t)l * 4194304, tmp, tmp2,
        ffb2 + (size_t)l * DMODEL, 2048, 4096, 4096, 1024);
    ln_residual_kernel<<<2048, 256, 0, stream>>>(
        h, h_bf, tmp, tmp2, ln2g + (size_t)l * DMODEL, ln2b + (size_t)l * DMODEL,
        (l == NLAYER - 1) ? (float*)d_out : nullptr);
  }
}